// Round 8
// baseline (119.491 us; speedup 1.0000x reference)
//
#include <hip/hip_runtime.h>

// PointPillarScatter: scatter sparse pillar features into a dense BEV grid.
// Grid: NX=432, NY=496, NZ=1, C=64, B=8, P=96000 pillars (5.6% occupancy).
// Out 0: [B, C, NY, NX] f32 ; Out 1: [B, 1, NY, NX] f32, concatenated flat.
//
// Round-8: round-7 (linear sweep + nt stores, 107.4us) + 4-way WAVE-COALESCED
// unroll: each wave owns 256 consecutive float4s; lane L writes base+i*64+L.
// Every store stays a fully-coalesced 1KB wave store; the wave's 4 map loads
// cover one contiguous 4KB window; one plane/batch L2 window per wave.
// (Rounds 5/6 ILP attempts failed for address-pattern reasons: 2t,2t+1 broke
// coalescing; g,g+half doubled the per-XCD L2 working set.)

namespace {

constexpr int kNX = 432;
constexpr int kNY = 496;
constexpr int kS  = kNX * kNY;   // 214272 spatial cells per sample
constexpr int kS4 = kS / 4;      // 53568 float4s per plane
constexpr int kC  = 64;
constexpr int kB  = 8;

typedef float f32x4 __attribute__((ext_vector_type(4)));

__global__ void scatter_idx_kernel(const int* __restrict__ coords,
                                   int* __restrict__ map,
                                   int P, int BS) {
  int p = blockIdx.x * blockDim.x + threadIdx.x;
  if (p >= P) return;
  // coords row p = (b, z, y, x) as int32
  int4 c = reinterpret_cast<const int4*>(coords)[p];
  long flat = (long)c.x * kS + (long)c.y + (long)c.z * kNX + (long)c.w;
  if (flat >= 0 && flat < (long)BS) map[(int)flat] = p;
}

// Wave-coalesced 4-way unroll: wave w owns float4s [w*256, w*256+256);
// lane L handles g = w*256 + i*64 + L, i = 0..3.
// plane 0..511   -> out0 (b = plane>>6, c = plane&63)
// plane 512..519 -> out1 (b = plane-512)
__global__ __launch_bounds__(256) void gather_fill_kernel(
    const int* __restrict__ map,     // [B*S] pillar index or -1
    const float* __restrict__ pf,    // [P, 64]
    const float* __restrict__ vnp,   // [P]
    float* __restrict__ out,
    int total4) {
  int t = blockIdx.x * blockDim.x + threadIdx.x;
  int lane = t & 63;
  int base = (t >> 6) * 256 + lane;
  const int4* __restrict__ map4 = reinterpret_cast<const int4*>(map);
  f32x4* __restrict__ out4 = reinterpret_cast<f32x4*>(out);

  #pragma unroll
  for (int i = 0; i < 4; ++i) {
    int g = base + i * 64;
    if (g >= total4) return;
    int plane = g / kS4;             // const-div -> mul_hi
    int j = g - plane * kS4;

    f32x4 v = (f32x4)(0.f);
    if (plane < kB * kC) {
      int b = plane >> 6;
      int c = plane & 63;
      int4 m = map4[b * kS4 + j];
      if ((m.x >= 0) | (m.y >= 0) | (m.z >= 0) | (m.w >= 0)) {
        if (m.x >= 0) v.x = pf[m.x * kC + c];
        if (m.y >= 0) v.y = pf[m.y * kC + c];
        if (m.z >= 0) v.z = pf[m.z * kC + c];
        if (m.w >= 0) v.w = pf[m.w * kC + c];
      }
    } else {
      int b = plane - kB * kC;
      int4 m = map4[b * kS4 + j];
      if (m.x >= 0) v.x = vnp[m.x];
      if (m.y >= 0) v.y = vnp[m.y];
      if (m.z >= 0) v.z = vnp[m.z];
      if (m.w >= 0) v.w = vnp[m.w];
    }
    // streaming store: evict-first / no L2 allocate; output is never re-read
    __builtin_nontemporal_store(v, out4 + g);
  }
}

// ---- fallback if ws_size is too small for the map: memset + direct scatter
__global__ void direct_scatter_kernel(const int* __restrict__ coords,
                                      const float* __restrict__ pf,
                                      const float* __restrict__ vnp,
                                      float* __restrict__ out,
                                      int P, int B) {
  int p = blockIdx.x;          // one wave per pillar
  int c = threadIdx.x;         // 64 channels
  if (p >= P) return;
  int4 cc = reinterpret_cast<const int4*>(coords)[p];
  int b = cc.x;
  int s = cc.y + cc.z * kNX + cc.w;
  out[(b * kC + c) * kS + s] = pf[p * kC + c];
  if (c == 0) out[B * kC * kS + b * kS + s] = vnp[p];
}

}  // namespace

extern "C" void kernel_launch(void* const* d_in, const int* in_sizes, int n_in,
                              void* d_out, int out_size, void* d_ws, size_t ws_size,
                              hipStream_t stream) {
  const float* pf     = (const float*)d_in[0];  // [P,64] f32
  const int*   coords = (const int*)d_in[1];    // [P,4] int32 (b,z,y,x)
  const float* vnp    = (const float*)d_in[2];  // [P] f32
  const int B = kB;                              // fixed by problem config
  const int P = in_sizes[0] / kC;
  const int BS = B * kS;                         // 1,714,176
  float* out = (float*)d_out;

  const size_t map_bytes = (size_t)BS * sizeof(int);
  if (ws_size >= map_bytes) {
    int* map = (int*)d_ws;
    (void)hipMemsetAsync(map, 0xFF, map_bytes, stream);  // all -1
    scatter_idx_kernel<<<(P + 255) / 256, 256, 0, stream>>>(coords, map, P, BS);
    const int total4 = (B * kC * kS + B * kS) / 4;  // 27,855,360 float4s
    const int nthreads = total4 / 4;                // 6,963,840 (divisible)
    gather_fill_kernel<<<(nthreads + 255) / 256, 256, 0, stream>>>(
        map, pf, vnp, out, total4);
  } else {
    (void)hipMemsetAsync(out, 0, (size_t)out_size * sizeof(float), stream);
    direct_scatter_kernel<<<P, 64, 0, stream>>>(coords, pf, vnp, out, P, B);
  }
}

// Round 9
// 111.318 us; speedup vs baseline: 1.0734x; 1.0734x over previous
//
#include <hip/hip_runtime.h>

// PointPillarScatter: scatter sparse pillar features into a dense BEV grid.
// Grid: NX=432, NY=496, NZ=1, C=64, B=8, P=96000 pillars (5.6% occupancy).
// Out 0: [B, C, NY, NX] f32 ; Out 1: [B, 1, NY, NX] f32, concatenated flat.
//
// Round-9: round-8's wave-coalesced 4-way unroll, with the in-loop
// `if (g >= total4) return;` removed. That guard made later map loads
// control-dependent on earlier stores -> the 4 "independent" chains
// serialized (load->use->store->branch x4), explaining r8's 119.5us.
// total4 = 108,810 * 256 exactly, so a wave-uniform upfront guard suffices;
// loads are all issued before any store (explicit two-phase body).

namespace {

constexpr int kNX = 432;
constexpr int kNY = 496;
constexpr int kS  = kNX * kNY;   // 214272 spatial cells per sample
constexpr int kS4 = kS / 4;      // 53568 float4s per plane
constexpr int kC  = 64;
constexpr int kB  = 8;

typedef float f32x4 __attribute__((ext_vector_type(4)));

__global__ void scatter_idx_kernel(const int* __restrict__ coords,
                                   int* __restrict__ map,
                                   int P, int BS) {
  int p = blockIdx.x * blockDim.x + threadIdx.x;
  if (p >= P) return;
  // coords row p = (b, z, y, x) as int32
  int4 c = reinterpret_cast<const int4*>(coords)[p];
  long flat = (long)c.x * kS + (long)c.y + (long)c.z * kNX + (long)c.w;
  if (flat >= 0 && flat < (long)BS) map[(int)flat] = p;
}

// Wave w owns float4s [w*256, w*256+256); lane L handles g = w*256 + i*64 + L.
// plane 0..511   -> out0 (b = plane>>6, c = plane&63)
// plane 512..519 -> out1 (b = plane-512)
__global__ __launch_bounds__(256) void gather_fill_kernel(
    const int* __restrict__ map,     // [B*S] pillar index or -1
    const float* __restrict__ pf,    // [P, 64]
    const float* __restrict__ vnp,   // [P]
    float* __restrict__ out,
    int nwaves) {                    // total4 / 256 = 108,810
  int t = blockIdx.x * blockDim.x + threadIdx.x;
  int lane = t & 63;
  int w = t >> 6;
  if (w >= nwaves) return;           // wave-uniform, outside the unroll
  const int4* __restrict__ map4 = reinterpret_cast<const int4*>(map);
  f32x4* __restrict__ out4 = reinterpret_cast<f32x4*>(out);
  int base = w * 256 + lane;

  // Phase 1: issue all 4 map loads (independent, in flight together).
  int4 m[4];
  int  ch[4];
  bool feat[4];
  #pragma unroll
  for (int i = 0; i < 4; ++i) {
    int g = base + i * 64;
    int plane = g / kS4;             // const-div -> mul_hi
    int j = g - plane * kS4;
    bool isf = plane < kB * kC;
    int b = isf ? (plane >> 6) : (plane - kB * kC);
    ch[i] = plane & 63;
    feat[i] = isf;
    m[i] = map4[b * kS4 + j];
  }

  // Phase 2: gather + streaming store.
  #pragma unroll
  for (int i = 0; i < 4; ++i) {
    f32x4 v = (f32x4)(0.f);
    int4 mm = m[i];
    if (feat[i]) {
      int c = ch[i];
      if (mm.x >= 0) v.x = pf[mm.x * kC + c];
      if (mm.y >= 0) v.y = pf[mm.y * kC + c];
      if (mm.z >= 0) v.z = pf[mm.z * kC + c];
      if (mm.w >= 0) v.w = pf[mm.w * kC + c];
    } else {
      if (mm.x >= 0) v.x = vnp[mm.x];
      if (mm.y >= 0) v.y = vnp[mm.y];
      if (mm.z >= 0) v.z = vnp[mm.z];
      if (mm.w >= 0) v.w = vnp[mm.w];
    }
    __builtin_nontemporal_store(v, out4 + base + i * 64);
  }
}

// ---- fallback if ws_size is too small for the map: memset + direct scatter
__global__ void direct_scatter_kernel(const int* __restrict__ coords,
                                      const float* __restrict__ pf,
                                      const float* __restrict__ vnp,
                                      float* __restrict__ out,
                                      int P, int B) {
  int p = blockIdx.x;          // one wave per pillar
  int c = threadIdx.x;         // 64 channels
  if (p >= P) return;
  int4 cc = reinterpret_cast<const int4*>(coords)[p];
  int b = cc.x;
  int s = cc.y + cc.z * kNX + cc.w;
  out[(b * kC + c) * kS + s] = pf[p * kC + c];
  if (c == 0) out[B * kC * kS + b * kS + s] = vnp[p];
}

}  // namespace

extern "C" void kernel_launch(void* const* d_in, const int* in_sizes, int n_in,
                              void* d_out, int out_size, void* d_ws, size_t ws_size,
                              hipStream_t stream) {
  const float* pf     = (const float*)d_in[0];  // [P,64] f32
  const int*   coords = (const int*)d_in[1];    // [P,4] int32 (b,z,y,x)
  const float* vnp    = (const float*)d_in[2];  // [P] f32
  const int B = kB;                              // fixed by problem config
  const int P = in_sizes[0] / kC;
  const int BS = B * kS;                         // 1,714,176
  float* out = (float*)d_out;

  const size_t map_bytes = (size_t)BS * sizeof(int);
  if (ws_size >= map_bytes) {
    int* map = (int*)d_ws;
    (void)hipMemsetAsync(map, 0xFF, map_bytes, stream);  // all -1
    scatter_idx_kernel<<<(P + 255) / 256, 256, 0, stream>>>(coords, map, P, BS);
    const int total4 = (B * kC * kS + B * kS) / 4;  // 27,855,360 float4s
    const int nwaves = total4 / 256;                // 108,810 exact
    const int nthreads = nwaves * 64;               // 6,963,840
    gather_fill_kernel<<<(nthreads + 255) / 256, 256, 0, stream>>>(
        map, pf, vnp, out, nwaves);
  } else {
    (void)hipMemsetAsync(out, 0, (size_t)out_size * sizeof(float), stream);
    direct_scatter_kernel<<<P, 64, 0, stream>>>(coords, pf, vnp, out, P, B);
  }
}

// Round 10
// 101.424 us; speedup vs baseline: 1.1781x; 1.0975x over previous
//
#include <hip/hip_runtime.h>

// PointPillarScatter: scatter sparse pillar features into a dense BEV grid.
// Grid: NX=432, NY=496, NZ=1, C=64, B=8, P=96000 pillars (5.6% occupancy).
// Out 0: [B, C, NY, NX] f32 ; Out 1: [B, 1, NY, NX] f32, concatenated flat.
//
// Round-10: EXACT round-7 structure (1 float4/thread linear sweep + nt
// stores, 107.4us — the best; all multi-float4/thread variants were worse),
// one variable changed: the occupancy map is int16 instead of int32.
// Per-batch pillar index < 12000 fits 16 bits (0xFFFF = empty;
// pillar = b*12000 + m). Halves the map memset (6.9->3.4 MB) and the
// 64x map re-read L2 stream (446->223 MB) that rides alongside the
// 446 MB store-fill stream.

namespace {

constexpr int kNX = 432;
constexpr int kNY = 496;
constexpr int kS  = kNX * kNY;   // 214272 spatial cells per sample
constexpr int kS4 = kS / 4;      // 53568 float4s per plane
constexpr int kC  = 64;
constexpr int kB  = 8;

typedef float f32x4 __attribute__((ext_vector_type(4)));
typedef unsigned short u16;
typedef u16 u16x4 __attribute__((ext_vector_type(4)));

__global__ void scatter_idx_kernel(const int* __restrict__ coords,
                                   u16* __restrict__ map,
                                   int P, int PB, int BS) {
  int p = blockIdx.x * blockDim.x + threadIdx.x;
  if (p >= P) return;
  // coords row p = (b, z, y, x) as int32
  int4 c = reinterpret_cast<const int4*>(coords)[p];
  long flat = (long)c.x * kS + (long)c.y + (long)c.z * kNX + (long)c.w;
  if (flat >= 0 && flat < (long)BS) map[(int)flat] = (u16)(p - c.x * PB);
}

// One thread = one output float4, swept linearly over the whole 446 MB.
// plane 0..511   -> out0 (b = plane>>6, c = plane&63)
// plane 512..519 -> out1 (b = plane-512)
__global__ __launch_bounds__(256) void gather_fill_kernel(
    const u16* __restrict__ map,     // [B*S] per-batch pillar idx or 0xFFFF
    const float* __restrict__ pf,    // [P, 64]
    const float* __restrict__ vnp,   // [P]
    float* __restrict__ out,
    int total4, int PB) {
  int g = blockIdx.x * blockDim.x + threadIdx.x;
  if (g >= total4) return;
  int plane = g / kS4;               // const-div -> mul_hi
  int j = g - plane * kS4;           // float4 index within plane

  f32x4 v = (f32x4)(0.f);
  if (plane < kB * kC) {
    int b = plane >> 6;
    int c = plane & 63;
    u16x4 m = reinterpret_cast<const u16x4*>(map)[b * kS4 + j];
    if ((m.x & m.y & m.z & m.w) != 0xFFFF) {   // any occupied
      int pb = b * PB;
      if (m.x != 0xFFFF) v.x = pf[(pb + m.x) * kC + c];
      if (m.y != 0xFFFF) v.y = pf[(pb + m.y) * kC + c];
      if (m.z != 0xFFFF) v.z = pf[(pb + m.z) * kC + c];
      if (m.w != 0xFFFF) v.w = pf[(pb + m.w) * kC + c];
    }
  } else {
    int b = plane - kB * kC;
    u16x4 m = reinterpret_cast<const u16x4*>(map)[b * kS4 + j];
    int pb = b * PB;
    if (m.x != 0xFFFF) v.x = vnp[pb + m.x];
    if (m.y != 0xFFFF) v.y = vnp[pb + m.y];
    if (m.z != 0xFFFF) v.z = vnp[pb + m.z];
    if (m.w != 0xFFFF) v.w = vnp[pb + m.w];
  }
  // streaming store: evict-first / no L2 allocate; output is never re-read
  __builtin_nontemporal_store(v, reinterpret_cast<f32x4*>(out) + g);
}

// ---- fallback if ws_size is too small for the map: memset + direct scatter
__global__ void direct_scatter_kernel(const int* __restrict__ coords,
                                      const float* __restrict__ pf,
                                      const float* __restrict__ vnp,
                                      float* __restrict__ out,
                                      int P, int B) {
  int p = blockIdx.x;          // one wave per pillar
  int c = threadIdx.x;         // 64 channels
  if (p >= P) return;
  int4 cc = reinterpret_cast<const int4*>(coords)[p];
  int b = cc.x;
  int s = cc.y + cc.z * kNX + cc.w;
  out[(b * kC + c) * kS + s] = pf[p * kC + c];
  if (c == 0) out[B * kC * kS + b * kS + s] = vnp[p];
}

}  // namespace

extern "C" void kernel_launch(void* const* d_in, const int* in_sizes, int n_in,
                              void* d_out, int out_size, void* d_ws, size_t ws_size,
                              hipStream_t stream) {
  const float* pf     = (const float*)d_in[0];  // [P,64] f32
  const int*   coords = (const int*)d_in[1];    // [P,4] int32 (b,z,y,x)
  const float* vnp    = (const float*)d_in[2];  // [P] f32
  const int B = kB;                              // fixed by problem config
  const int P = in_sizes[0] / kC;
  const int PB = P / B;                          // 12000 pillars per batch
  const int BS = B * kS;                         // 1,714,176
  float* out = (float*)d_out;

  const size_t map_bytes = (size_t)BS * sizeof(u16);
  if (ws_size >= map_bytes && PB <= 0xFFFF) {
    u16* map = (u16*)d_ws;
    (void)hipMemsetAsync(map, 0xFF, map_bytes, stream);  // all 0xFFFF = empty
    scatter_idx_kernel<<<(P + 255) / 256, 256, 0, stream>>>(coords, map, P, PB, BS);
    const int total4 = (B * kC * kS + B * kS) / 4;  // 27,855,360 float4s
    gather_fill_kernel<<<(total4 + 255) / 256, 256, 0, stream>>>(
        map, pf, vnp, out, total4, PB);
  } else {
    (void)hipMemsetAsync(out, 0, (size_t)out_size * sizeof(float), stream);
    direct_scatter_kernel<<<P, 64, 0, stream>>>(coords, pf, vnp, out, P, B);
  }
}